// Round 7
// baseline (531.560 us; speedup 1.0000x reference)
//
#include <hip/hip_runtime.h>
#include <math.h>

#define NCLS 100
#define NBINS 15
// conf cells use swizzled index c*15 + (c>>2) + b : bank stride 61 per sub
// (61 coprime with 32) -> 25 distinct banks, 2-way across halves (free).
// Padded for junk classes c in [100,128) from inactive lanes (they add 0.0).
#define CONF_CELLS 1952
#define ACC_CELLS  (NCLS * NBINS)
#define RPI 4   // row-pairs per iteration (8 rows per wave iteration)

__device__ __forceinline__ void fadd(float* p, float v) { unsafeAtomicAdd(p, v); }

template <int CTRL>
__device__ __forceinline__ float dpp_add(float x) {
    int y = __builtin_amdgcn_update_dpp(0, __builtin_bit_cast(int, x),
                                        CTRL, 0xf, 0xf, true);
    return x + __builtin_bit_cast(float, y);
}

// Layout: wave = 2 rows. half = lane>>5 (row parity), sub = lane&31,
// lanes sub<25 active, each holds float4 = classes 4sub..4sub+3.
// One dwordx4 load serves both rows; one 5-step DPP chain sums both rows
// (lane31 = row A total, lane63 = row B total).
__global__ __launch_bounds__(256) void ece_main_kernel(
    const float* __restrict__ logits,
    const int* __restrict__ labels,
    float* __restrict__ g_conf,
    float* __restrict__ g_acc,
    int N)
{
    __shared__ float s_conf[CONF_CELLS];
    __shared__ float s_acc[ACC_CELLS];
    for (int i = threadIdx.x; i < CONF_CELLS; i += 256) s_conf[i] = 0.f;
    for (int i = threadIdx.x; i < ACC_CELLS; i += 256) s_acc[i] = 0.f;
    __syncthreads();

    const int lane = threadIdx.x & 63;
    const int wave = threadIdx.x >> 6;
    const int half = lane >> 5;
    const int sub  = lane & 31;
    const bool act = (sub < 25);

    const int gwave  = blockIdx.x * 4 + wave;
    const int nwaves = gridDim.x * 4;

    // Loop-invariant swizzled conf bases for the 4 owned classes;
    // -1 folds the (bin-1) of the reference's ceil(p*15)-1.
    int cbase[4];
    #pragma unroll
    for (int j = 0; j < 4; ++j) {
        const int c = 4 * sub + j;
        cbase[j] = c * NBINS + (c >> 2) - 1;
    }

    for (int base = gwave * (2 * RPI); base < N; base += nwaves * (2 * RPI)) {
        #pragma unroll
        for (int i = 0; i < RPI; ++i) {
            const int row = base + 2 * i + half;
            const bool v = act && (row < N);
            float4 x = make_float4(-1000.f, -1000.f, -1000.f, -1000.f);
            if (v) x = *(const float4*)(logits + (size_t)row * NCLS + 4 * sub);

            const int rA = base + 2 * i;
            const int rB = rA + 1;
            const int labA = (rA < N) ? labels[rA] : 1000;  // sentinel: no lane matches
            const int labB = (rB < N) ? labels[rB] : 1000;

            float4 e;
            e.x = __expf(x.x); e.y = __expf(x.y);
            e.z = __expf(x.z); e.w = __expf(x.w);   // exp(-1000)=0 for inactive
            float s = (e.x + e.y) + (e.z + e.w);
            s = dpp_add<0x111>(s);   // row_shr:1
            s = dpp_add<0x112>(s);   // row_shr:2
            s = dpp_add<0x114>(s);   // row_shr:4
            s = dpp_add<0x118>(s);   // row_shr:8  -> lane15/31/47/63 hold 16-sums
            s = dpp_add<0x142>(s);   // row_bcast:15 -> lane31 = rowA, lane63 = rowB
            const float totA = __builtin_bit_cast(float,
                __builtin_amdgcn_readlane(__builtin_bit_cast(int, s), 31));
            const float totB = __builtin_bit_cast(float,
                __builtin_amdgcn_readlane(__builtin_bit_cast(int, s), 63));
            float tot = half ? totB : totA;
            tot = fmaxf(tot, 1e-30f);       // padding rows: tot=0 -> p=0, no NaN
            const float inv = 1.0f / tot;   // exact IEEE divide (matches ref)

            float4 p;
            p.x = e.x * inv; p.y = e.y * inv;
            p.z = e.z * inv; p.w = e.w * inv;
            // reference bin: ceil(p*15)-1 clipped to [0,14]; bi here = bin+1
            int b0 = (int)ceilf(p.x * 15.f);
            int b1 = (int)ceilf(p.y * 15.f);
            int b2 = (int)ceilf(p.z * 15.f);
            int b3 = (int)ceilf(p.w * 15.f);
            b0 = min(max(b0, 1), 15); b1 = min(max(b1, 1), 15);
            b2 = min(max(b2, 1), 15); b3 = min(max(b3, 1), 15);
            // branchless conf accumulation (p==0 adds 0.0: harmless)
            fadd(&s_conf[cbase[0] + b0], p.x);
            fadd(&s_conf[cbase[1] + b1], p.y);
            fadd(&s_conf[cbase[2] + b2], p.z);
            fadd(&s_conf[cbase[3] + b3], p.w);

            // acc: exactly one lane per valid row owns the label class
            const int labSel = half ? labB : labA;
            if (sub == (labSel >> 2)) {
                const int sel = labSel & 3;
                const int bs = (sel == 0) ? b0 : (sel == 1) ? b1
                             : (sel == 2) ? b2 : b3;
                fadd(&s_acc[labSel * NBINS + bs - 1], 1.f);
            }
        }
    }

    __syncthreads();
    for (int i = threadIdx.x; i < CONF_CELLS; i += 256) {
        const float v = s_conf[i];
        if (v != 0.f) fadd(&g_conf[i], v);
    }
    for (int i = threadIdx.x; i < ACC_CELLS; i += 256) {
        const float a = s_acc[i];
        if (a != 0.f) fadd(&g_acc[i], a);
    }
}

// Finalize: per-class sum_b |conf - acc| / N (conf via swizzled index), mean.
__global__ __launch_bounds__(128) void ece_final_kernel(
    const float* __restrict__ g_conf,
    const float* __restrict__ g_acc,
    float* __restrict__ out,
    float invN)
{
    __shared__ float red[128];
    const int t = threadIdx.x;
    float s = 0.f;
    if (t < NCLS) {
        const int cb = t * NBINS + (t >> 2);
        float sum = 0.f;
        #pragma unroll
        for (int b = 0; b < NBINS; ++b)
            sum += fabsf(g_conf[cb + b] - g_acc[t * NBINS + b]);
        s = sum * invN;
        out[1 + t] = s;
    }
    red[t] = s;
    __syncthreads();
    #pragma unroll
    for (int off = 64; off > 0; off >>= 1) {
        if (t < off) red[t] += red[t + off];
        __syncthreads();
    }
    if (t == 0) out[0] = red[0] * (1.0f / (float)NCLS);
}

extern "C" void kernel_launch(void* const* d_in, const int* in_sizes, int n_in,
                              void* d_out, int out_size, void* d_ws, size_t ws_size,
                              hipStream_t stream)
{
    const float* logits = (const float*)d_in[0];
    const int*   labels = (const int*)d_in[1];
    const int N = in_sizes[1];
    float* out = (float*)d_out;

    float* g_conf = (float*)d_ws;            // [CONF_CELLS]
    float* g_acc  = g_conf + CONF_CELLS;     // [ACC_CELLS]

    (void)hipMemsetAsync(d_ws, 0, (size_t)(CONF_CELLS + ACC_CELLS) * sizeof(float),
                         stream);

    const int blocks = 2048;   // 8 blocks/CU, ~13.8 KB LDS each
    ece_main_kernel<<<blocks, 256, 0, stream>>>(logits, labels, g_conf, g_acc, N);
    ece_final_kernel<<<1, 128, 0, stream>>>(g_conf, g_acc, out, 1.0f / (float)N);
}

// Round 8
// 352.079 us; speedup vs baseline: 1.5098x; 1.5098x over previous
//
#include <hip/hip_runtime.h>
#include <math.h>

#define NCLS 100
#define NBINS 15
#define NSEG (NCLS * NBINS)
#define RPI 8   // rows per wave iteration: all loads issued before any use

// Native fp32 atomic add (ds_add_f32 / global_atomic_add_f32).
__device__ __forceinline__ void fadd(float* p, float v) { unsafeAtomicAdd(p, v); }

// DPP wave64 sum step (VALU pipe only). 6-step chain -> lane 63 holds total.
template <int CTRL>
__device__ __forceinline__ float dpp_add(float x) {
    int y = __builtin_amdgcn_update_dpp(0, __builtin_bit_cast(int, x),
                                        CTRL, 0xf, 0xf, true);
    return x + __builtin_bit_cast(float, y);
}

// Wave-per-row, lanes = classes (c, c+64). Per iteration: 16 row-loads +
// 1 label load ALL issued up front (decoupled from consumption), then exps,
// then 8 interleaved DPP chains, then 8 independent row tails with rcp.
__global__ __launch_bounds__(256) void ece_main_kernel(
    const float* __restrict__ logits,
    const int* __restrict__ labels,
    float* __restrict__ g_total,
    float* __restrict__ g_conf,
    float* __restrict__ g_acc,
    int N)
{
    __shared__ float s_total[NCLS];
    __shared__ float s_conf[NSEG];
    __shared__ float s_acc[NSEG];
    for (int i = threadIdx.x; i < NSEG; i += 256) { s_conf[i] = 0.f; s_acc[i] = 0.f; }
    if (threadIdx.x < NCLS) s_total[threadIdx.x] = 0.f;
    __syncthreads();

    const int lane   = threadIdx.x & 63;
    const int wave   = threadIdx.x >> 6;
    const int gwave  = blockIdx.x * 4 + wave;
    const int nwaves = gridDim.x * 4;

    const int c0 = lane;
    const int c1 = lane + 64;
    const bool has1 = (c1 < NCLS);     // lanes 0..35

    float t0 = 0.f, t1 = 0.f;          // lane-private per-class prob totals

    for (int base = gwave * RPI; base < N; base += nwaves * RPI) {
        // Batched labels: lane l holds labels[base+l]; distributed via readlane.
        const int labv = labels[min(base + lane, N - 1)];

        float e0[RPI], e1[RPI], s[RPI];

        // Phase 1: issue ALL loads (raw logits land in e0/e1).
        #pragma unroll
        for (int r = 0; r < RPI; ++r) {
            const int row = base + r;               // wave-uniform
            const bool v = (row < N);
            const float* rp = logits + (size_t)row * NCLS;
            e0[r] = v ? rp[c0] : -1000.f;           // coalesced 256B
            e1[r] = (v && has1) ? rp[c1] : -1000.f; // coalesced 144B
        }

        // Phase 2: exp in place (exp(-1000) flushes to 0 for pad lanes/rows).
        #pragma unroll
        for (int r = 0; r < RPI; ++r) {
            e0[r] = __expf(e0[r]);
            e1[r] = __expf(e1[r]);
            s[r] = e0[r] + e1[r];
        }

        // Phase 3: 8 interleaved DPP chains (depth 6, 8-way ILP).
        #pragma unroll
        for (int r = 0; r < RPI; ++r) s[r] = dpp_add<0x111>(s[r]); // row_shr:1
        #pragma unroll
        for (int r = 0; r < RPI; ++r) s[r] = dpp_add<0x112>(s[r]); // row_shr:2
        #pragma unroll
        for (int r = 0; r < RPI; ++r) s[r] = dpp_add<0x114>(s[r]); // row_shr:4
        #pragma unroll
        for (int r = 0; r < RPI; ++r) s[r] = dpp_add<0x118>(s[r]); // row_shr:8
        #pragma unroll
        for (int r = 0; r < RPI; ++r) s[r] = dpp_add<0x142>(s[r]); // bcast:15
        #pragma unroll
        for (int r = 0; r < RPI; ++r) s[r] = dpp_add<0x143>(s[r]); // bcast:31

        // Phase 4: independent row tails (rcp, bins, rare atomics).
        #pragma unroll
        for (int r = 0; r < RPI; ++r) {
            const float tot = __builtin_bit_cast(float,
                __builtin_amdgcn_readlane(__builtin_bit_cast(int, s[r]), 63));
            const float inv = __builtin_amdgcn_rcpf(fmaxf(tot, 1e-30f));
            const int lab = (base + r < N)
                          ? __builtin_amdgcn_readlane(labv, r) : -1;

            const float p0 = e0[r] * inv;
            t0 += p0;
            int b0 = min((int)ceilf(p0 * 15.f) - 1, NBINS - 1);  // -1 iff p==0
            if (b0 >= 1) fadd(&s_conf[c0 * NBINS + b0], p0);     // ~0.8% lanes
            if (c0 == lab) fadd(&s_acc[c0 * NBINS + max(b0, 0)], 1.f);

            const float p1 = e1[r] * inv;
            t1 += p1;
            int b1 = min((int)ceilf(p1 * 15.f) - 1, NBINS - 1);
            if (b1 >= 1) fadd(&s_conf[c1 * NBINS + b1], p1);
            if (has1 && c1 == lab) fadd(&s_acc[c1 * NBINS + max(b1, 0)], 1.f);
        }
    }

    // Flush lane-private totals, then block-local histograms, to global.
    fadd(&s_total[c0], t0);
    if (has1) fadd(&s_total[c1], t1);
    __syncthreads();

    for (int i = threadIdx.x; i < NSEG; i += 256) {
        float v = s_conf[i]; if (v != 0.f) fadd(&g_conf[i], v);
        float a = s_acc[i];  if (a != 0.f) fadd(&g_acc[i], a);
    }
    if (threadIdx.x < NCLS) {
        float t = s_total[threadIdx.x];
        if (t != 0.f) fadd(&g_total[threadIdx.x], t);
    }
}

// Finalize: conf0 = total - sum_{b>=1} conf_b; per-class sce; mean.
__global__ __launch_bounds__(128) void ece_final_kernel(
    const float* __restrict__ g_total,
    const float* __restrict__ g_conf,
    const float* __restrict__ g_acc,
    float* __restrict__ out,
    float invN)
{
    __shared__ float red[128];
    const int t = threadIdx.x;
    float s = 0.f;
    if (t < NCLS) {
        float conf0 = g_total[t];
        float sum = 0.f;
        #pragma unroll
        for (int b = 1; b < NBINS; ++b) {
            float cb = g_conf[t * NBINS + b];
            float ab = g_acc[t * NBINS + b];
            conf0 -= cb;
            sum += fabsf(cb - ab);
        }
        sum += fabsf(conf0 - g_acc[t * NBINS + 0]);
        s = sum * invN;
        out[1 + t] = s;
    }
    red[t] = s;
    __syncthreads();
    #pragma unroll
    for (int off = 64; off > 0; off >>= 1) {
        if (t < off) red[t] += red[t + off];
        __syncthreads();
    }
    if (t == 0) out[0] = red[0] * (1.0f / (float)NCLS);
}

extern "C" void kernel_launch(void* const* d_in, const int* in_sizes, int n_in,
                              void* d_out, int out_size, void* d_ws, size_t ws_size,
                              hipStream_t stream)
{
    const float* logits = (const float*)d_in[0];
    const int*   labels = (const int*)d_in[1];
    const int N = in_sizes[1];
    float* out = (float*)d_out;

    float* g_total = (float*)d_ws;          // [NCLS]
    float* g_conf  = g_total + NCLS;        // [NSEG]
    float* g_acc   = g_conf + NSEG;         // [NSEG]

    (void)hipMemsetAsync(d_ws, 0, (size_t)(NCLS + 2 * NSEG) * sizeof(float), stream);

    // 2048 blocks = 8 blocks/CU (12.8 KB LDS; VGPR must stay <=64).
    const int blocks = 2048;
    ece_main_kernel<<<blocks, 256, 0, stream>>>(logits, labels,
                                                g_total, g_conf, g_acc, N);
    ece_final_kernel<<<1, 128, 0, stream>>>(g_total, g_conf, g_acc, out,
                                            1.0f / (float)N);
}